// Round 6
// baseline (88.742 us; speedup 1.0000x reference)
//
#include <hip/hip_runtime.h>

// Hankel anti-diagonal segmented mean.
// Input:  delay_embedding [B=64, T=1024, E=2048] fp32
// Output: [B, E-1=2047] fp32; out[b,k] = mean over i of A[b, i, 1024+k-i],
//         i in [max(0, k-1023), 1023].
//
// Diagonal walk: for fixed row i, elements for consecutive k are contiguous:
// A[b,i,1024+k-i] = in[b*T*E + i*(E-1) + (T+k)].  Each input element is read
// exactly once (402 MB -> HBM-bound, ~64 us floor).
//
// R6: wave unit = (b, 512-k group G, 32-row chunk rc); thread owns 8 k's ->
// wave reads 2 KB CONTIGUOUS per row (two dwordx4/lane), half the row-jumps
// of R5 (DRAM page locality + ILP). 112 units/batch in 28 blocks:
//   u2  0- 7: heavy G=0, waves -> rc = 4*u2+w          (32 full units)
//   u2  8-15: heavy G=1, rc = 4*(u2-8)+w               (32 full units)
//   u2 16-19: heavy G=2, rc = 16+4*(u2-16)+w           (16 full units)
//   u2 20-27: light l=u2-20: waves {G2 rc=2l, G2 2l+1, G3 31-2l, G3 30-2l}
//             (weight W2(rc)+W3(31-rc) = const -> each light block = 2 f.e.)
// With bid = u2*64+b, every CU gets exactly 5 heavy + 2 light = 24 f.e.
// Waves store 8 partials to private LDS; barrier; combine same-G waves and
// unsafeAtomicAdd (HW f32 atomic) the 1/cnt-scaled means into memset'd out.

#define T_LEN 1024
#define E_LEN 2048
#define K_OUT (E_LEN - 1)   // 2047
#define B_SZ  64
#define NBLK  (28 * B_SZ)   // 1792

__global__ void __launch_bounds__(256, 7)
diag_accum(const float* __restrict__ in, float* __restrict__ out) {
    __shared__ float lacc[2048];   // 8 KB: [wave][512 k-slots]

    const int b    = blockIdx.x & (B_SZ - 1);
    const int u2   = blockIdx.x >> 6;        // 0..27
    const int w    = threadIdx.x >> 6;       // wave 0..3
    const int lane = threadIdx.x & 63;

    int G, rc;
    bool light = false;
    if (u2 < 8)       { G = 0; rc = (u2 << 2) | w; }
    else if (u2 < 16) { G = 1; rc = ((u2 - 8) << 2) | w; }
    else if (u2 < 20) { G = 2; rc = 16 + ((u2 - 16) << 2) + w; }
    else {
        light = true;
        const int l = u2 - 20;               // 0..7
        if (w == 0)      { G = 2; rc = 2 * l;      }
        else if (w == 1) { G = 2; rc = 2 * l + 1;  }
        else if (w == 2) { G = 3; rc = 31 - 2 * l; }
        else             { G = 3; rc = 30 - 2 * l; }
    }

    const int k0 = (G << 9) + (lane << 3);   // 8 consecutive k's
    const int r0 = rc << 5;                  // 32-row chunk
    const int r1 = r0 + 32;

    const int il0 = max(r0, k0 - (T_LEN - 1));        // first row any comp valid
    int ilc       = max(r0, k0 - (T_LEN - 1) + 7);    // first row all 8 valid
    if (ilc > r1) ilc = r1;

    float s[8] = {0.f, 0.f, 0.f, 0.f, 0.f, 0.f, 0.f, 0.f};
    if (il0 < r1) {
        const float* p = in + (size_t)b * T_LEN * E_LEN
                            + (size_t)il0 * (E_LEN - 1)
                            + (size_t)(T_LEN + k0);
        int i = il0;

        // Ragged diagonal head (<=7 iters): load only valid components
        // (also keeps the b=63, i=1023, k0=2040 corner inside the buffer).
        for (; i < ilc; ++i) {
            const int mc = i + (T_LEN - 1) - k0;   // comp c valid iff c <= mc
            #pragma unroll
            for (int c = 0; c < 8; ++c)
                if (c <= mc) s[c] += p[c];
            p += (E_LEN - 1);
        }

        // Main loop: all 8 components valid and in-row (j <= 2047).
        #pragma unroll 2
        for (; i < r1; ++i) {
            float v0[4], v1[4];
            __builtin_memcpy(v0, p,     16);   // unaligned-safe -> dwordx4
            __builtin_memcpy(v1, p + 4, 16);
            s[0] += v0[0]; s[1] += v0[1]; s[2] += v0[2]; s[3] += v0[3];
            s[4] += v1[0]; s[5] += v1[1]; s[6] += v1[2]; s[7] += v1[3];
            p += (E_LEN - 1);
        }
    }

    // Private LDS region per wave (plain stores, no init: idle lanes wrote 0).
    float4* dst = (float4*)&lacc[(w << 9) + (lane << 3)];
    dst[0] = make_float4(s[0], s[1], s[2], s[3]);
    dst[1] = make_float4(s[4], s[5], s[6], s[7]);
    __syncthreads();

    if (!light) {
        // All 4 waves share the same 512-k span.
        #pragma unroll 2
        for (int t = threadIdx.x; t < 512; t += 256) {
            const int k = (G << 9) + t;            // G<=2 here -> k <= 1535
            const float v = lacc[t] + lacc[512 + t] + lacc[1024 + t] + lacc[1536 + t];
            const int cnt = T_LEN - max(0, k - (T_LEN - 1));
            unsafeAtomicAdd(&out[(size_t)b * K_OUT + k], v * (1.0f / (float)cnt));
        }
    } else {
        // Waves {0,1} -> k in [1024,1536); waves {2,3} -> k in [1536,2048).
        #pragma unroll 4
        for (int t = threadIdx.x; t < 1024; t += 256) {
            const int seg = t >> 9, tl = t & 511;
            const int k = 1024 + (seg << 9) + tl;
            if (k < K_OUT) {                       // drop k = 2047
                const float v = lacc[(seg << 10) + tl] + lacc[(seg << 10) + 512 + tl];
                const int cnt = T_LEN - max(0, k - (T_LEN - 1));
                unsafeAtomicAdd(&out[(size_t)b * K_OUT + k], v * (1.0f / (float)cnt));
            }
        }
    }
}

extern "C" void kernel_launch(void* const* d_in, const int* in_sizes, int n_in,
                              void* d_out, int out_size, void* d_ws, size_t ws_size,
                              hipStream_t stream) {
    const float* in = (const float*)d_in[0];
    float* out = (float*)d_out;

    // Zero the accumulator (d_out is poisoned once, never re-poisoned).
    hipMemsetAsync(out, 0, sizeof(float) * B_SZ * K_OUT, stream);

    diag_accum<<<NBLK, 256, 0, stream>>>(in, out);
}